// Round 8
// baseline (215.278 us; speedup 1.0000x reference)
//
#include <hip/hip_runtime.h>
#include <hip/hip_bf16.h>

// ---------- types ----------
typedef __attribute__((ext_vector_type(8))) short bf16x8;   // 4 VGPR MFMA A/B frag
typedef __attribute__((ext_vector_type(4))) float f32x4;    // 4 VGPR MFMA C/D frag
typedef __attribute__((ext_vector_type(4))) unsigned int uint4v;
typedef __attribute__((address_space(1))) const unsigned int gu32;
typedef __attribute__((address_space(3))) unsigned int lu32;

__device__ __forceinline__ unsigned short f2bf(float f) {
    __hip_bfloat16 h = __float2bfloat16(f);   // RNE
    return __builtin_bit_cast(unsigned short, h);
}

template<int N> __device__ __forceinline__ void waitv() {
    asm volatile("s_waitcnt vmcnt(%0)" :: "i"(N) : "memory");
}
__device__ __forceinline__ void waitlgkm0() {
    asm volatile("s_waitcnt lgkmcnt(0)" ::: "memory");
}

// Problem constants: B=16, C=768, H=W=48 -> HW=2304, tokens/mod = 36864
#define BT 256            // tokens per block (1KB contiguous channel-runs)
#define TPM 144           // tiles per modality = 36864/256
#define NCHUNK 24         // 768 / 32

// ---------- precompute: partial u/v sums (u = g.W1 col-sums, v = b.W1) ----------
__global__ void prep_partial(const float* __restrict__ w1, const float* __restrict__ lng,
                             const float* __restrict__ lnb,
                             float* __restrict__ upart, float* __restrict__ vpart)
{
    const int m   = blockIdx.x >> 3;
    const int seg = blockIdx.x & 7;
    const int d   = threadIdx.x;          // 192 threads
    const float* w1m = w1 + (size_t)m * 768 * 192;
    const float* gm  = lng + m * 768;
    const float* bm  = lnb + m * 768;
    const int c0 = seg * 96;
    float su = 0.f, sv = 0.f;
    for (int c = 0; c < 96; ++c) {
        float wv = w1m[(size_t)(c0 + c) * 192 + d];
        su += gm[c0 + c] * wv;
        sv += bm[c0 + c] * wv;
    }
    upart[(m * 8 + seg) * 192 + d] = su;
    vpart[(m * 8 + seg) * 192 + d] = sv;
}

__global__ void prep_combine(const float* __restrict__ upart, const float* __restrict__ vpart,
                             const float* __restrict__ b1,
                             float* __restrict__ u, float* __restrict__ vb)
{
    const int m = blockIdx.x;
    const int d = threadIdx.x;            // 192 threads
    float su = 0.f, sv = 0.f;
    for (int s = 0; s < 8; ++s) {
        su += upart[(m * 8 + s) * 192 + d];
        sv += vpart[(m * 8 + s) * 192 + d];
    }
    u[m * 192 + d]  = su;
    vb[m * 192 + d] = sv + b1[m * 192 + d];
}

// ---------- precompute: pack g*W1 as bf16 in MFMA B-fragment order ----------
// w1f[m][kk(24)][nf(12)][lane(64)][8]; B-frag lane l holds B[k=(l>>4)*8+j][n=l&15].
__global__ void prep_pack(const float* __restrict__ w1, const float* __restrict__ lng,
                          unsigned short* __restrict__ w1f)
{
    const int m  = blockIdx.x / 24;
    const int kk = blockIdx.x % 24;
    const int tid = threadIdx.x;          // 256 threads
    __shared__ float ws[32 * 192];
    const float* w1m = w1 + ((size_t)m * 768 + kk * 32) * 192;
    const float* gm  = lng + m * 768 + kk * 32;
    for (int i = tid; i < 6144; i += 256) {
        int cl = i / 192, d = i % 192;
        ws[i] = gm[cl] * w1m[(size_t)cl * 192 + d];
    }
    __syncthreads();
    unsigned short* outp = w1f + ((size_t)m * 24 + kk) * 6144;
    for (int i = tid; i < 6144; i += 256) {
        int nf   = i >> 9;
        int rem  = i & 511;
        int lane = rem >> 3;
        int j    = rem & 7;
        int cl   = ((lane >> 4) << 3) + j;
        int d    = (nf << 4) + (lane & 15);
        outp[i]  = f2bf(ws[cl * 192 + d]);
    }
}

// ---------- fused main kernel ----------
// 1024 thr (16 waves), 256 tokens/block. Wave w = (wi = w&3, wj = w>>2):
// tokens [wi*64,+64) x dims [wj*48,+48); acc 4x3 f32x4 = 48 VGPR.
//
// vmem instruction budget (the R6->R7 lever): 44 wave-instrs/chunk/block
// (32 A gload_lds 1KB single-segment + 12 B gload_lds 1KB L2-hot), down from
// R6's 80 (B-frags now distributed via LDS: 3 ds_read_b128/wave, 16B/lane
// contiguous = fast per m134).
//
// Per chunk k (2 raw barriers, loads in flight across both):
//   waitv (own chunk-k ops retired: w<12 -> 3, else 2; see below)
//   bar1        (all waves' chunk-k stages published: F[k&1], Blds[k%3])
//   pack:       F[k&1] f32 -> stats + bf16 At[k&1] (8 b32 reads, 1 b128 write)
//   lgkm0; bar2 (At ready; F[k&1] free)
//   STAGE(k+2): A -> F[k&1] (2/wave), B -> Blds[(k+2)%3] (1 for w<12)
//   LDB: 3 ds_read_b128 from Blds[k%3]; MFMA(k): At[k&1] x B
//
// Per-wave vmcnt (issue order per chunk pinned [A,A,(B)]; in-order retire):
//   top(k), k=0..22: outstanding = chunk k+1 stages only = 3 (w<12) / 2 (w>=12)
//   top(23): 0.  Chunk k+2 is issued mid-step k, after its buffers free.
// Blds triple-buffer: stage(k+2) overwrites slot of chunk k-1, whose ds_reads
// completed 2 barriers prior. At[k&1] WAR: pack(k+2) is 2 barriers after
// MFMA(k)'s reads. F[k&1] WAR: all pack reads done at bar2.
__global__ __launch_bounds__(1024, 4)
void fused_main(const float* __restrict__ f0, const float* __restrict__ f1,
                const float* __restrict__ f2,
                const unsigned short* __restrict__ w1f,
                const float* __restrict__ u_g, const float* __restrict__ vb_g,
                const float* __restrict__ w2_g, const float* __restrict__ b2_g,
                float* __restrict__ out)
{
    const int bx   = blockIdx.x;
    const int mod  = bx / TPM;
    const int tile = bx % TPM;
    const float* feat = (mod == 0) ? f0 : ((mod == 1) ? f1 : f2);
    const int T0   = tile * BT;
    const int bimg = T0 / 2304;
    const int hw0  = T0 % 2304;               // 256 | 2304: no image crossing
    const float* fbase = feat + (size_t)bimg * 768 * 2304 + hw0;

    const int tid  = threadIdx.x;
    const int l    = tid & 63;
    const int w    = tid >> 6;     // wave 0..15
    const int wi   = w & 3;        // token quarter
    const int wj   = w >> 2;       // dim quarter (48 dims)
    const int tokp = tid & 255;    // pack role: token
    const int cg   = tid >> 8;     // pack role: 8-ch group
    const int col  = l & 15, lg = l >> 4;

    __shared__ float F[2][32][256];              // 64 KB A staging queue
    __shared__ unsigned short At[2][256][40];    // 40 KB bf16, 80B rows
    __shared__ unsigned short Blds[3][6144];     // 36 KB B staging (12KB/chunk)
    __shared__ float Sred[4][256], Qred[4][256]; // 8 KB
    __shared__ float mu_s[256], rs_s[256];       // 2 KB
    __shared__ float red2[4][256];               // 4 KB   (total ~154 KB)

    const unsigned short* w1fm = w1f + (size_t)mod * 24 * 6144;

    f32x4 acc[4][3];
    #pragma unroll
    for (int a = 0; a < 4; ++a)
        #pragma unroll
        for (int b = 0; b < 3; ++b) acc[a][b] = (f32x4){0.f, 0.f, 0.f, 0.f};

    float sum = 0.f, ssq = 0.f;

    // STAGE chunk kk: A rows (2 per wave, 1KB contiguous each) + B frag (w<12)
    auto STAGE = [&](int kk, int fbuf, int b3) {
        #pragma unroll
        for (int c = 0; c < 2; ++c) {
            const float* src = fbase + (size_t)(kk * 32 + 2 * w + c) * 2304 + 4 * l;
            __builtin_amdgcn_global_load_lds((gu32*)src,
                                             (lu32*)&F[fbuf][2 * w + c][0], 16, 0, 0);
        }
        if (w < 12) {
            const unsigned short* bsrc = w1fm + (size_t)kk * 6144 + w * 512 + l * 8;
            __builtin_amdgcn_global_load_lds((gu32*)bsrc,
                                             (lu32*)&Blds[b3][w * 512], 16, 0, 0);
        }
        __builtin_amdgcn_sched_barrier(0);
    };

#define STEPK(KK, BUF, B3, DO_S)                                               \
    {                                                                          \
        if ((KK) < 23) { if (w < 12) waitv<3>(); else waitv<2>(); }            \
        else           { waitv<0>(); }                                         \
        __builtin_amdgcn_sched_barrier(0);                                     \
        __builtin_amdgcn_s_barrier();   /* bar1: F[BUF], Blds[B3] published */ \
        __builtin_amdgcn_sched_barrier(0);                                     \
        float xs[8];                                                           \
        _Pragma("unroll")                                                      \
        for (int jj = 0; jj < 8; ++jj) {                                       \
            xs[jj] = F[BUF][cg * 8 + jj][tokp];                                \
            sum += xs[jj]; ssq = fmaf(xs[jj], xs[jj], ssq);                    \
        }                                                                      \
        uint4v pk;                                                             \
        _Pragma("unroll")                                                      \
        for (int jj = 0; jj < 4; ++jj) {                                       \
            unsigned lo = (unsigned)f2bf(xs[2 * jj]);                          \
            unsigned hi = (unsigned)f2bf(xs[2 * jj + 1]);                      \
            pk[jj] = lo | (hi << 16);                                          \
        }                                                                      \
        *reinterpret_cast<uint4v*>(&At[BUF][tokp][cg * 8]) = pk;               \
        waitlgkm0();                                                           \
        __builtin_amdgcn_sched_barrier(0);                                     \
        __builtin_amdgcn_s_barrier();   /* bar2: At ready; F[BUF] free */      \
        __builtin_amdgcn_sched_barrier(0);                                     \
        if (DO_S) STAGE((KK) + 2, BUF, ((KK) + 2) % 3);                        \
        bf16x8 bq[3];                                                          \
        _Pragma("unroll")                                                      \
        for (int nf = 0; nf < 3; ++nf)                                         \
            bq[nf] = *reinterpret_cast<const bf16x8*>(                         \
                &Blds[B3][((wj * 3 + nf) * 64 + l) * 8]);                      \
        bf16x8 af[4];                                                          \
        _Pragma("unroll")                                                      \
        for (int mf = 0; mf < 4; ++mf) {                                       \
            int t = wi * 64 + mf * 16 + col;                                   \
            af[mf] = *reinterpret_cast<const bf16x8*>(&At[BUF][t][lg * 8]);    \
        }                                                                      \
        _Pragma("unroll")                                                      \
        for (int mf = 0; mf < 4; ++mf)                                         \
            _Pragma("unroll")                                                  \
            for (int nf = 0; nf < 3; ++nf)                                     \
                acc[mf][nf] = __builtin_amdgcn_mfma_f32_16x16x32_bf16(         \
                                  af[mf], bq[nf], acc[mf][nf], 0, 0, 0);       \
    }

    // ---- prologue: chunk0 [A,A,B], chunk1 [A,A,B] (order pinned) ----
    STAGE(0, 0, 0);
    STAGE(1, 1, 1);
    __builtin_amdgcn_sched_barrier(0);

    STEPK(0, 0, 0, true)   STEPK(1, 1, 1, true)   STEPK(2, 0, 2, true)
    STEPK(3, 1, 0, true)   STEPK(4, 0, 1, true)   STEPK(5, 1, 2, true)
    STEPK(6, 0, 0, true)   STEPK(7, 1, 1, true)   STEPK(8, 0, 2, true)
    STEPK(9, 1, 0, true)   STEPK(10, 0, 1, true)  STEPK(11, 1, 2, true)
    STEPK(12, 0, 0, true)  STEPK(13, 1, 1, true)  STEPK(14, 0, 2, true)
    STEPK(15, 1, 0, true)  STEPK(16, 0, 1, true)  STEPK(17, 1, 2, true)
    STEPK(18, 0, 0, true)  STEPK(19, 1, 1, true)  STEPK(20, 0, 2, true)
    STEPK(21, 1, 0, true)
    STEPK(22, 0, 1, false)
    STEPK(23, 1, 2, false)
#undef STEPK

    // ---- LayerNorm stats (per token over all 768 ch) ----
    Sred[cg][tokp] = sum;
    Qred[cg][tokp] = ssq;
    __syncthreads();
    if (tid < 256) {
        float S = Sred[0][tid] + Sred[1][tid] + Sred[2][tid] + Sred[3][tid];
        float Q = Qred[0][tid] + Qred[1][tid] + Qred[2][tid] + Qred[3][tid];
        float mu = S * (1.f / 768.f);
        float var = Q * (1.f / 768.f) - mu * mu;
        mu_s[tid] = mu;
        rs_s[tid] = rsqrtf(var + 1e-5f);
    }
    __syncthreads();

    // ---- epilogue: affine LN fix + GELU + dot(w2) + sigmoid ----
    const float* um  = u_g  + mod * 192;
    const float* vbm = vb_g + mod * 192;
    const float* w2m = w2_g + mod * 192;
    float uf[3], vbf[3], w2f[3];
    #pragma unroll
    for (int nf = 0; nf < 3; ++nf) {
        int d = wj * 48 + nf * 16 + col;
        uf[nf] = um[d]; vbf[nf] = vbm[d]; w2f[nf] = w2m[d];
    }
    float ps[4][4];
    #pragma unroll
    for (int mf = 0; mf < 4; ++mf) {
        #pragma unroll
        for (int r = 0; r < 4; ++r) {
            int t = wi * 64 + mf * 16 + lg * 4 + r;   // C/D: row=(lane>>4)*4+reg
            float mu = mu_s[t], rs = rs_s[t];
            float pp = 0.f;
            #pragma unroll
            for (int nf = 0; nf < 3; ++nf) {
                float x = rs * (acc[mf][nf][r] - mu * uf[nf]) + vbf[nf];
                float h = 0.5f * x * (1.f + erff(x * 0.70710678118f));  // exact GELU
                pp += h * w2f[nf];
            }
            ps[mf][r] = pp;
        }
    }
    #pragma unroll
    for (int m = 1; m < 16; m <<= 1)
        #pragma unroll
        for (int mf = 0; mf < 4; ++mf)
            #pragma unroll
            for (int r = 0; r < 4; ++r)
                ps[mf][r] += __shfl_xor(ps[mf][r], m, 64);
    if (col == 0) {
        #pragma unroll
        for (int mf = 0; mf < 4; ++mf)
            #pragma unroll
            for (int r = 0; r < 4; ++r)
                red2[wj][wi * 64 + mf * 16 + lg * 4 + r] = ps[mf][r];
    }
    __syncthreads();
    if (tid < 256) {
        float logit = red2[0][tid] + red2[1][tid] + red2[2][tid] + red2[3][tid] + b2_g[mod];
        out[(size_t)mod * 36864 + T0 + tid] = 1.f / (1.f + expf(-logit));
    }
}

// ---------- launch ----------
extern "C" void kernel_launch(void* const* d_in, const int* in_sizes, int n_in,
                              void* d_out, int out_size, void* d_ws, size_t ws_size,
                              hipStream_t stream)
{
    const float* f0  = (const float*)d_in[0];
    const float* f1  = (const float*)d_in[1];
    const float* f2  = (const float*)d_in[2];
    const float* lng = (const float*)d_in[3];
    const float* lnb = (const float*)d_in[4];
    const float* w1  = (const float*)d_in[5];
    const float* b1  = (const float*)d_in[6];
    const float* w2  = (const float*)d_in[7];
    const float* b2  = (const float*)d_in[8];
    float* out = (float*)d_out;

    char* ws = (char*)d_ws;
    unsigned short* w1f = (unsigned short*)ws;          // 884736 B
    float* u     = (float*)(ws + 884736);               // 2304 B
    float* vb    = (float*)(ws + 887040);               // 2304 B
    float* upart = (float*)(ws + 889344);               // 18432 B
    float* vpart = (float*)(ws + 907776);               // 18432 B

    prep_partial<<<dim3(24), dim3(192), 0, stream>>>(w1, lng, lnb, upart, vpart);
    prep_combine<<<dim3(3),  dim3(192), 0, stream>>>(upart, vpart, b1, u, vb);
    prep_pack   <<<dim3(72), dim3(256), 0, stream>>>(w1, lng, w1f);
    fused_main  <<<dim3(3 * TPM), dim3(1024), 0, stream>>>(f0, f1, f2, w1f, u, vb, w2, b2, out);
}

// Round 9
// 129.621 us; speedup vs baseline: 1.6608x; 1.6608x over previous
//
#include <hip/hip_runtime.h>
#include <hip/hip_bf16.h>

// ---------- types ----------
typedef __attribute__((ext_vector_type(8))) short bf16x8;   // 4 VGPR MFMA A/B frag
typedef __attribute__((ext_vector_type(4))) float f32x4;    // 4 VGPR MFMA C/D frag
typedef __attribute__((ext_vector_type(4))) unsigned int uint4v;

__device__ __forceinline__ unsigned short f2bf(float f) {
    __hip_bfloat16 h = __float2bfloat16(f);   // RNE
    return __builtin_bit_cast(unsigned short, h);
}
__device__ __forceinline__ void waitlgkm0() {
    asm volatile("s_waitcnt lgkmcnt(0)" ::: "memory");
}

// Problem constants: B=16, C=768, H=W=48 -> HW=2304, tokens/mod = 36864
#define BT 128            // tokens per block
#define TPM 288           // tiles per modality = 36864/128
#define NCHUNK 24         // 768 / 32

// ---------- precompute: partial u/v sums (u = g.W1 col-sums, v = b.W1) ----------
__global__ void prep_partial(const float* __restrict__ w1, const float* __restrict__ lng,
                             const float* __restrict__ lnb,
                             float* __restrict__ upart, float* __restrict__ vpart)
{
    const int m   = blockIdx.x >> 3;
    const int seg = blockIdx.x & 7;
    const int d   = threadIdx.x;          // 192 threads
    const float* w1m = w1 + (size_t)m * 768 * 192;
    const float* gm  = lng + m * 768;
    const float* bm  = lnb + m * 768;
    const int c0 = seg * 96;
    float su = 0.f, sv = 0.f;
    for (int c = 0; c < 96; ++c) {
        float wv = w1m[(size_t)(c0 + c) * 192 + d];
        su += gm[c0 + c] * wv;
        sv += bm[c0 + c] * wv;
    }
    upart[(m * 8 + seg) * 192 + d] = su;
    vpart[(m * 8 + seg) * 192 + d] = sv;
}

__global__ void prep_combine(const float* __restrict__ upart, const float* __restrict__ vpart,
                             const float* __restrict__ b1,
                             float* __restrict__ u, float* __restrict__ vb)
{
    const int m = blockIdx.x;
    const int d = threadIdx.x;            // 192 threads
    float su = 0.f, sv = 0.f;
    for (int s = 0; s < 8; ++s) {
        su += upart[(m * 8 + s) * 192 + d];
        sv += vpart[(m * 8 + s) * 192 + d];
    }
    u[m * 192 + d]  = su;
    vb[m * 192 + d] = sv + b1[m * 192 + d];
}

// ---------- precompute: pack g*W1 as bf16 in MFMA B-fragment order ----------
// w1f[m][kk(24)][nf(12)][lane(64)][8]; B-frag lane l holds B[k=(l>>4)*8+j][n=l&15].
__global__ void prep_pack(const float* __restrict__ w1, const float* __restrict__ lng,
                          unsigned short* __restrict__ w1f)
{
    const int m  = blockIdx.x / 24;
    const int kk = blockIdx.x % 24;
    const int tid = threadIdx.x;          // 256 threads
    __shared__ float ws[32 * 192];
    const float* w1m = w1 + ((size_t)m * 768 + kk * 32) * 192;
    const float* gm  = lng + m * 768 + kk * 32;
    for (int i = tid; i < 6144; i += 256) {
        int cl = i / 192, d = i % 192;
        ws[i] = gm[cl] * w1m[(size_t)cl * 192 + d];
    }
    __syncthreads();
    unsigned short* outp = w1f + ((size_t)m * 24 + kk) * 6144;
    for (int i = tid; i < 6144; i += 256) {
        int nf   = i >> 9;
        int rem  = i & 511;
        int lane = rem >> 3;
        int j    = rem & 7;
        int cl   = ((lane >> 4) << 3) + j;
        int d    = (nf << 4) + (lane & 15);
        outp[i]  = f2bf(ws[cl * 192 + d]);
    }
}

// ---------- fused main kernel ----------
// 512 thr (8 waves), 128 tokens/block, 2 blocks/CU. Wave w: wi = w&1 (token
// half), wj = w>>1 (dim quarter); acc 4x3 f32x4 = 48 VGPR.
//
// R9 experiment: ZERO global_load_lds. A-chunk -> VGPRs (2x dwordx4/thread,
// thread covers ch {4w+2s, 4w+2s+1}, toks 4*lane32..+3; 512B segments),
// then ds_write to F[32][132] f32 (transpose buffer). B -> register loads
// (R6-proven L2-cached). Compiler auto-inserts counted vmcnt for all reg
// consumers; raw s_barriers keep loads in flight across steps.
//
// Per chunk k (2 raw barriers):
//   ds_write F from regs(k); lgkm0        (reg WAR cleared)
//   LOADA(k+2) -> just-freed regs         (2-chunk lead)
//   bar1                                  (F published)
//   pack: F tok-major reads (conflict-free) -> stats + bf16 At[k&1] (1 b128)
//   lgkm0; bar2                           (At ready; F free for k+1)
//   MFMA(k): At[k&1] x bq(k);  LOADB(k+1) -> other bq
// F single-buffer safe: all F(k) reads complete before each wave's bar2(k);
// F(k+1) writes occur after bar2(k). At[k&1]: readers (MFMA(k)) drain before
// own bar1(k+1) (lgkm0 at step k+1 covers); writer pack(k+2) after bar1(k+2).
__global__ __launch_bounds__(512, 4)
void fused_main(const float* __restrict__ f0, const float* __restrict__ f1,
                const float* __restrict__ f2,
                const unsigned short* __restrict__ w1f,
                const float* __restrict__ u_g, const float* __restrict__ vb_g,
                const float* __restrict__ w2_g, const float* __restrict__ b2_g,
                float* __restrict__ out)
{
    const int bx   = blockIdx.x;
    const int mod  = bx / TPM;
    const int tile = bx % TPM;
    const float* feat = (mod == 0) ? f0 : ((mod == 1) ? f1 : f2);
    const int T0   = tile * BT;
    const int bimg = T0 / 2304;
    const int hw0  = T0 % 2304;               // 128 | 2304: no image crossing
    const float* fbase = feat + (size_t)bimg * 768 * 2304 + hw0;

    const int tid    = threadIdx.x;
    const int l      = tid & 63;
    const int w      = tid >> 6;     // wave 0..7
    const int s      = l >> 5;       // channel half within wave's 4-ch slot
    const int lane32 = l & 31;       // token quad
    const int tokp   = tid & 127;    // pack role: token
    const int cg     = tid >> 7;     // pack role: 8-ch group (== wj)
    const int col    = l & 15, lg = l >> 4;
    const int wi     = w & 1;        // token half (MFMA)
    const int wj     = w >> 1;       // dim quarter (MFMA)
    const int chA    = 4 * w + 2 * s;  // thread's channel base in each chunk

    __shared__ float F[32][132];                 // 16.9 KB transpose buffer
    __shared__ unsigned short At[2][128][40];    // 20 KB bf16, 80B rows
    __shared__ float Sred[4][128], Qred[4][128]; // 4 KB
    __shared__ float mu_s[128], rs_s[128];       // 1 KB
    __shared__ float red2[4][128];               // 2 KB  (total ~44 KB)

    const unsigned short* w1fm = w1f + (size_t)mod * 24 * 6144;

    f32x4 acc[4][3];
    #pragma unroll
    for (int a = 0; a < 4; ++a)
        #pragma unroll
        for (int b = 0; b < 3; ++b) acc[a][b] = (f32x4){0.f, 0.f, 0.f, 0.f};

    float sum = 0.f, ssq = 0.f;
    bf16x8 bqA[3], bqB[3];
    f32x4 aA0, aA1, aB0, aB1;       // named double-buffered A regs (rule #20)

    auto LOADA = [&](int kk, f32x4& r0, f32x4& r1) {
        const float* p = fbase + (size_t)(kk * 32 + chA) * 2304 + 4 * lane32;
        r0 = *reinterpret_cast<const f32x4*>(p);
        r1 = *reinterpret_cast<const f32x4*>(p + 2304);
    };
    auto LOADB = [&](int kk, bf16x8 (&bq)[3]) {
        const bf16x8* sB = reinterpret_cast<const bf16x8*>(w1fm + (size_t)kk * 6144);
        #pragma unroll
        for (int nf = 0; nf < 3; ++nf)
            bq[nf] = sB[(wj * 3 + nf) * 64 + l];     // 16B/lane, L2-hot
    };

#define STEPK(KK, A0, A1, BQU, BQL, DO_A, DO_B)                                \
    {                                                                          \
        /* publish A-chunk KK from regs into F (auto counted-vmcnt wait) */    \
        *reinterpret_cast<f32x4*>(&F[chA + 0][4 * lane32]) = A0;               \
        *reinterpret_cast<f32x4*>(&F[chA + 1][4 * lane32]) = A1;               \
        waitlgkm0();                                                           \
        __builtin_amdgcn_sched_barrier(0);                                     \
        if (DO_A) LOADA((KK) + 2, A0, A1);   /* regs freed by lgkm0 */         \
        __builtin_amdgcn_sched_barrier(0);                                     \
        __builtin_amdgcn_s_barrier();        /* bar1: F published */           \
        __builtin_amdgcn_sched_barrier(0);                                     \
        float xs[8];                                                           \
        _Pragma("unroll")                                                      \
        for (int jj = 0; jj < 8; ++jj) {                                       \
            xs[jj] = F[cg * 8 + jj][tokp];                                     \
            sum += xs[jj]; ssq = fmaf(xs[jj], xs[jj], ssq);                    \
        }                                                                      \
        uint4v pk;                                                             \
        _Pragma("unroll")                                                      \
        for (int jj = 0; jj < 4; ++jj) {                                       \
            unsigned lo = (unsigned)f2bf(xs[2 * jj]);                          \
            unsigned hi = (unsigned)f2bf(xs[2 * jj + 1]);                      \
            pk[jj] = lo | (hi << 16);                                          \
        }                                                                      \
        *reinterpret_cast<uint4v*>(&At[(KK) & 1][tokp][cg * 8]) = pk;          \
        waitlgkm0();                                                           \
        __builtin_amdgcn_sched_barrier(0);                                     \
        __builtin_amdgcn_s_barrier();        /* bar2: At ready; F free */      \
        __builtin_amdgcn_sched_barrier(0);                                     \
        bf16x8 af[4];                                                          \
        _Pragma("unroll")                                                      \
        for (int mf = 0; mf < 4; ++mf) {                                       \
            int t = wi * 64 + mf * 16 + col;                                   \
            af[mf] = *reinterpret_cast<const bf16x8*>(&At[(KK) & 1][t][lg * 8]); \
        }                                                                      \
        _Pragma("unroll")                                                      \
        for (int mf = 0; mf < 4; ++mf)                                         \
            _Pragma("unroll")                                                  \
            for (int nf = 0; nf < 3; ++nf)                                     \
                acc[mf][nf] = __builtin_amdgcn_mfma_f32_16x16x32_bf16(         \
                                  af[mf], BQU[nf], acc[mf][nf], 0, 0, 0);      \
        if (DO_B) LOADB((KK) + 1, BQL);                                        \
    }

    // ---- prologue ----
    LOADA(0, aA0, aA1);
    LOADA(1, aB0, aB1);
    LOADB(0, bqA);
    __builtin_amdgcn_sched_barrier(0);

    STEPK(0,  aA0, aA1, bqA, bqB, true, true)
    STEPK(1,  aB0, aB1, bqB, bqA, true, true)
    STEPK(2,  aA0, aA1, bqA, bqB, true, true)
    STEPK(3,  aB0, aB1, bqB, bqA, true, true)
    STEPK(4,  aA0, aA1, bqA, bqB, true, true)
    STEPK(5,  aB0, aB1, bqB, bqA, true, true)
    STEPK(6,  aA0, aA1, bqA, bqB, true, true)
    STEPK(7,  aB0, aB1, bqB, bqA, true, true)
    STEPK(8,  aA0, aA1, bqA, bqB, true, true)
    STEPK(9,  aB0, aB1, bqB, bqA, true, true)
    STEPK(10, aA0, aA1, bqA, bqB, true, true)
    STEPK(11, aB0, aB1, bqB, bqA, true, true)
    STEPK(12, aA0, aA1, bqA, bqB, true, true)
    STEPK(13, aB0, aB1, bqB, bqA, true, true)
    STEPK(14, aA0, aA1, bqA, bqB, true, true)
    STEPK(15, aB0, aB1, bqB, bqA, true, true)
    STEPK(16, aA0, aA1, bqA, bqB, true, true)
    STEPK(17, aB0, aB1, bqB, bqA, true, true)
    STEPK(18, aA0, aA1, bqA, bqB, true, true)
    STEPK(19, aB0, aB1, bqB, bqA, true, true)
    STEPK(20, aA0, aA1, bqA, bqB, true, true)
    STEPK(21, aB0, aB1, bqB, bqA, true, true)
    STEPK(22, aA0, aA1, bqA, bqB, false, true)
    STEPK(23, aB0, aB1, bqB, bqA, false, false)
#undef STEPK

    // ---- LayerNorm stats (per token over all 768 ch) ----
    Sred[cg][tokp] = sum;
    Qred[cg][tokp] = ssq;
    __syncthreads();
    if (tid < 128) {
        float S = Sred[0][tid] + Sred[1][tid] + Sred[2][tid] + Sred[3][tid];
        float Q = Qred[0][tid] + Qred[1][tid] + Qred[2][tid] + Qred[3][tid];
        float mu = S * (1.f / 768.f);
        float var = Q * (1.f / 768.f) - mu * mu;
        mu_s[tid] = mu;
        rs_s[tid] = rsqrtf(var + 1e-5f);
    }
    __syncthreads();

    // ---- epilogue: affine LN fix + GELU + dot(w2) + sigmoid ----
    const float* um  = u_g  + mod * 192;
    const float* vbm = vb_g + mod * 192;
    const float* w2m = w2_g + mod * 192;
    float uf[3], vbf[3], w2f[3];
    #pragma unroll
    for (int nf = 0; nf < 3; ++nf) {
        int d = wj * 48 + nf * 16 + col;
        uf[nf] = um[d]; vbf[nf] = vbm[d]; w2f[nf] = w2m[d];
    }
    float ps[4][4];
    #pragma unroll
    for (int mf = 0; mf < 4; ++mf) {
        #pragma unroll
        for (int r = 0; r < 4; ++r) {
            int t = wi * 64 + mf * 16 + lg * 4 + r;   // C/D: row=(lane>>4)*4+reg
            float mu = mu_s[t], rs = rs_s[t];
            float pp = 0.f;
            #pragma unroll
            for (int nf = 0; nf < 3; ++nf) {
                float x = rs * (acc[mf][nf][r] - mu * uf[nf]) + vbf[nf];
                float h = 0.5f * x * (1.f + erff(x * 0.70710678118f));  // exact GELU
                pp += h * w2f[nf];
            }
            ps[mf][r] = pp;
        }
    }
    #pragma unroll
    for (int m = 1; m < 16; m <<= 1)
        #pragma unroll
        for (int mf = 0; mf < 4; ++mf)
            #pragma unroll
            for (int r = 0; r < 4; ++r)
                ps[mf][r] += __shfl_xor(ps[mf][r], m, 64);
    if (col == 0) {
        #pragma unroll
        for (int mf = 0; mf < 4; ++mf)
            #pragma unroll
            for (int r = 0; r < 4; ++r)
                red2[wj][wi * 64 + mf * 16 + lg * 4 + r] = ps[mf][r];
    }
    __syncthreads();
    if (tid < 128) {
        float logit = red2[0][tid] + red2[1][tid] + red2[2][tid] + red2[3][tid] + b2_g[mod];
        out[(size_t)mod * 36864 + T0 + tid] = 1.f / (1.f + expf(-logit));
    }
}

// ---------- launch ----------
extern "C" void kernel_launch(void* const* d_in, const int* in_sizes, int n_in,
                              void* d_out, int out_size, void* d_ws, size_t ws_size,
                              hipStream_t stream)
{
    const float* f0  = (const float*)d_in[0];
    const float* f1  = (const float*)d_in[1];
    const float* f2  = (const float*)d_in[2];
    const float* lng = (const float*)d_in[3];
    const float* lnb = (const float*)d_in[4];
    const float* w1  = (const float*)d_in[5];
    const float* b1  = (const float*)d_in[6];
    const float* w2  = (const float*)d_in[7];
    const float* b2  = (const float*)d_in[8];
    float* out = (float*)d_out;

    char* ws = (char*)d_ws;
    unsigned short* w1f = (unsigned short*)ws;          // 884736 B
    float* u     = (float*)(ws + 884736);               // 2304 B
    float* vb    = (float*)(ws + 887040);               // 2304 B
    float* upart = (float*)(ws + 889344);               // 18432 B
    float* vpart = (float*)(ws + 907776);               // 18432 B

    prep_partial<<<dim3(24), dim3(192), 0, stream>>>(w1, lng, lnb, upart, vpart);
    prep_combine<<<dim3(3),  dim3(192), 0, stream>>>(upart, vpart, b1, u, vb);
    prep_pack   <<<dim3(72), dim3(256), 0, stream>>>(w1, lng, w1f);
    fused_main  <<<dim3(3 * TPM), dim3(512), 0, stream>>>(f0, f1, f2, w1f, u, vb, w2, b2, out);
}